// Round 17
// baseline (797.133 us; speedup 1.0000x reference)
//
#include <hip/hip_runtime.h>
#include <cstddef>
#include <cstdint>

// Problem constants (from reference): B=256, T=512, I=128, H=64, 4H=256.
#define NB 256
#define NT 512
#define H4 256

typedef _Float16 v2h  __attribute__((ext_vector_type(2)));
typedef _Float16 half8 __attribute__((ext_vector_type(8)));
typedef float float4v __attribute__((ext_vector_type(4)));
typedef int v4i __attribute__((ext_vector_type(4)));
typedef int v2i __attribute__((ext_vector_type(2)));

__device__ __forceinline__ int pack2h(float a, float b) {
    v2h p; p.x = (_Float16)a; p.y = (_Float16)b;
    return __builtin_bit_cast(int, p);
}

// ---------------------------------------------------------------------------
// Pack one weight matrix [256,64] f32 into MFMA A-fragment layout (f16).
// Frag (w, f=g*2+kt): lane l holds A[row][k] with
//   row = 16*(4g+w) + (l&15)
//   k   = 32*kt + 16*(e>>2) + (l>>4)*4 + (e&3)        (e = 0..7)
// (two-16-block k mapping per the hw tr-read evidence; the same convention is
// used for the B-side reads, so any global k-permutation cancels in A·B.)
// Stored per (w,f): 256 ints, lane-contiguous int4 -> one dwordx4 per frag.
// ---------------------------------------------------------------------------
__global__ void pack_wA(const float* __restrict__ W, int* __restrict__ out) {
    int idx = blockIdx.x * 256 + threadIdx.x;   // 0..8191
    int e2 = idx & 3;
    int l  = (idx >> 2) & 63;
    int f  = (idx >> 8) & 7;
    int w  = idx >> 11;
    int g = f >> 1, kt = f & 1;
    int row = 16 * (4 * g + w) + (l & 15);
    int k = 32 * kt + 16 * (e2 >> 1) + ((l >> 4) * 4) + 2 * (e2 & 1);
    out[idx] = pack2h(W[row * 64 + k], W[row * 64 + k + 1]);
}

// ---------------------------------------------------------------------------
// Transpose W [256, K] -> Wt [K, 256] (layer-0 GEMM only)
// ---------------------------------------------------------------------------
__global__ void transpose_w(const float* __restrict__ W, float* __restrict__ Wt, int K) {
    int idx = blockIdx.x * 256 + threadIdx.x;
    if (idx < 256 * K) {
        int n = idx / K, k = idx - n * K;
        Wt[k * 256 + n] = W[idx];
    }
}

// ---------------------------------------------------------------------------
// Input-projection GEMM for layer 0 (K=128), f32 output (proven).
// ---------------------------------------------------------------------------
template <int K>
__global__ __launch_bounds__(256) void gemm_xp(
    const float* __restrict__ X, const float* __restrict__ Wt,
    const float* __restrict__ b1, const float* __restrict__ b2,
    float* __restrict__ XP)
{
    constexpr int TM = 64;
    constexpr int KC = 16;
    __shared__ __align__(16) float xT[K][TM + 4];
    __shared__ __align__(16) float wc[KC][256];
    const int m0 = blockIdx.x * TM;
    const int t  = threadIdx.x;
    const int cg = (t & 63) * 4;
    const int rg = (t >> 6) * 16;

    for (int idx = t; idx < TM * K; idx += 256) {
        int r = idx / K, k = idx - r * K;
        xT[k][r] = X[(size_t)(m0 + r) * K + k];
    }

    float acc[16][4];
    #pragma unroll
    for (int i = 0; i < 16; ++i)
        #pragma unroll
        for (int j = 0; j < 4; ++j) acc[i][j] = 0.f;

    for (int kc = 0; kc < K; kc += KC) {
        __syncthreads();
        #pragma unroll
        for (int i = 0; i < 4; ++i) {
            int e4 = (t + i * 256) * 4;
            int k = e4 >> 8, n = e4 & 255;
            *(float4*)&wc[k][n] = *(const float4*)&Wt[(size_t)(kc + k) * 256 + n];
        }
        __syncthreads();
        #pragma unroll
        for (int k = 0; k < KC; ++k) {
            float4 w = *(const float4*)&wc[k][cg];
            float xr[16];
            #pragma unroll
            for (int q = 0; q < 4; ++q)
                *(float4*)&xr[q * 4] = *(const float4*)&xT[kc + k][rg + q * 4];
            #pragma unroll
            for (int rr = 0; rr < 16; ++rr) {
                acc[rr][0] += xr[rr] * w.x;
                acc[rr][1] += xr[rr] * w.y;
                acc[rr][2] += xr[rr] * w.z;
                acc[rr][3] += xr[rr] * w.w;
            }
        }
    }

    float bias[4];
    #pragma unroll
    for (int j = 0; j < 4; ++j) bias[j] = b1[cg + j] + b2[cg + j];
    #pragma unroll
    for (int rr = 0; rr < 16; ++rr) {
        float4 o;
        o.x = acc[rr][0] + bias[0];
        o.y = acc[rr][1] + bias[1];
        o.z = acc[rr][2] + bias[2];
        o.w = acc[rr][3] + bias[3];
        *(float4*)&XP[(size_t)(m0 + rg + rr) * 256 + cg] = o;
    }
}

// ---------------------------------------------------------------------------
// MFMA 3-layer wavefront-pipelined LSTM scan.
// 16 blocks x 16 batch elements. 12 waves: wave (L = w12>>2, w = w12&3).
// Wave (L,w) owns unit-tile w (units 16w..16w+15) x all 4 gates x 16 batches:
//   gates = Whh A-frags (regs) @ B(h^L_{t-1})  [+ Wih A-frags @ B(h^{L-1}_t)]
// via v_mfma_f32_16x16x32_f16; D layout (verified m89): row=(l>>4)*4+r,
// col=l&15 -> cell update is lane-local, 4 units (r) x 1 batch (col) per lane.
// h state: LDS hb[L][parity][batch 16][72-pad f16]; D-rows = 4 consecutive
// units -> one ds_write_b64 per lane; B-frags = 2x ds_read_b64 per k-tile.
// One barrier per pipeline step (lgkmcnt-only drain).
// ---------------------------------------------------------------------------
__global__ __launch_bounds__(768) void lstm_mfma(
    const float* __restrict__ xp,     // [B*T, 256] layer-0 xp f32 (incl. biases)
    const int* __restrict__ WPK,      // packed A-frags: 5 matrices x 8192 ints
    const float* __restrict__ bi1, const float* __restrict__ bh1,
    const float* __restrict__ bi2, const float* __restrict__ bh2,
    float* __restrict__ hl)           // [B, 64] layer-2 h at t = NT-1
{
    const int tid = threadIdx.x;
    const int bg = blockIdx.x;           // batches 16bg .. 16bg+15
    const int lane = tid & 63;
    const int lo = lane & 15;            // batch-in-group (MFMA col)
    const int hi = lane >> 4;            // lane group 0..3
    const int w12 = tid >> 6;
    const int Lu = __builtin_amdgcn_readfirstlane(w12 >> 2);   // layer 0..2
    const int wu = __builtin_amdgcn_readfirstlane(w12 & 3);    // unit-tile

    __shared__ __align__(16) _Float16 hb[3][2][16][72];   // 13824 B
    __shared__ __align__(16) float bias_lds[2][256];      // bi+bh, layers 1,2

    for (int i = tid; i < 3456; i += 768) ((int*)hb)[i] = 0;
    if (tid < 512) {
        int li = tid >> 8, row = tid & 255;
        bias_lds[li][row] = (li ? bi2[row] : bi1[row]) + (li ? bh2[row] : bh1[row]);
    }

    // Whh A-frags -> registers (8 frags x int4; f = gate*2 + ktile)
    half8 whh[8];
    {
        const v4i* wp = (const v4i*)(WPK
            + ((Lu == 0) ? 0 : (Lu == 1) ? 1 : 3) * 8192 + wu * 2048 + lane * 4);
        #pragma unroll
        for (int f = 0; f < 8; ++f) whh[f] = __builtin_bit_cast(half8, wp[f * 64]);
    }
    // Wih A-frags for layers 1,2
    half8 wih[8];
    if (Lu > 0) {
        const v4i* wp = (const v4i*)(WPK
            + ((Lu == 1) ? 2 : 4) * 8192 + wu * 2048 + lane * 4);
        #pragma unroll
        for (int f = 0; f < 8; ++f) wih[f] = __builtin_bit_cast(half8, wp[f * 64]);
    }

    // L0 acc-init source: xp rows 64g+16w+hi*4 .. +3 of batch 16bg+lo at time t
    const float* xpg = xp + (size_t)(16 * bg + lo) * NT * H4 + 16 * wu + hi * 4;

    float c0 = 0.f, c1 = 0.f, c2 = 0.f, c3 = 0.f;   // cell state (4 units/lane)

    asm volatile("s_waitcnt lgkmcnt(0)" ::: "memory");
    __builtin_amdgcn_s_barrier();
    __builtin_amdgcn_sched_barrier(0);

    const float LOG2E = 1.4426950408889634f;
#define SIG(x) __builtin_amdgcn_rcpf(1.f + __builtin_amdgcn_exp2f((x) * -LOG2E))
#define TH(x)  __builtin_fmaf(2.f, __builtin_amdgcn_rcpf(1.f + __builtin_amdgcn_exp2f((x) * (-2.f * LOG2E))), -1.f)
#define MFMA(A, B, C) __builtin_amdgcn_mfma_f32_16x16x32_f16((A), (B), (C), 0, 0, 0)

    for (int s = 0; s < NT + 2; ++s) {
        const int t = s - Lu;                      // wave-uniform
        if ((unsigned)t < NT) {
            const int pprev = (t + 1) & 1, pcur = t & 1;

            // ---- own-h B-fragments (k-tiles 0,1), two b64 reads each ----
            const _Float16* hp = &hb[Lu][pprev][lo][hi * 4];
            v2i a0 = *(const v2i*)(hp);
            v2i a1 = *(const v2i*)(hp + 16);
            v2i a2 = *(const v2i*)(hp + 32);
            v2i a3 = *(const v2i*)(hp + 48);
            v4i q0 = {a0.x, a0.y, a1.x, a1.y};
            v4i q1 = {a2.x, a2.y, a3.x, a3.y};
            half8 Bo0 = __builtin_bit_cast(half8, q0);
            half8 Bo1 = __builtin_bit_cast(half8, q1);

            float4v aI, aF, aG, aO;
            half8 Bi0 = {}, Bi1 = {};
            if (Lu == 0) {
                const float* xb = xpg + (size_t)t * H4;
                aI = *(const float4v*)(xb);
                aF = *(const float4v*)(xb + 64);
                aG = *(const float4v*)(xb + 128);
                aO = *(const float4v*)(xb + 192);
            } else {
                const _Float16* gp = &hb[Lu - 1][pcur][lo][hi * 4];
                v2i b0 = *(const v2i*)(gp);
                v2i b1 = *(const v2i*)(gp + 16);
                v2i b2 = *(const v2i*)(gp + 32);
                v2i b3 = *(const v2i*)(gp + 48);
                v4i u0 = {b0.x, b0.y, b1.x, b1.y};
                v4i u1 = {b2.x, b2.y, b3.x, b3.y};
                Bi0 = __builtin_bit_cast(half8, u0);
                Bi1 = __builtin_bit_cast(half8, u1);
                const float* bp = &bias_lds[Lu - 1][16 * wu + hi * 4];
                aI = *(const float4v*)(bp);
                aF = *(const float4v*)(bp + 64);
                aG = *(const float4v*)(bp + 128);
                aO = *(const float4v*)(bp + 192);
            }

            // ---- MFMA accumulation: gates = Whh.h (+ Wih.g) + init ----
            aI = MFMA(whh[0], Bo0, aI);  aI = MFMA(whh[1], Bo1, aI);
            aF = MFMA(whh[2], Bo0, aF);  aF = MFMA(whh[3], Bo1, aF);
            aG = MFMA(whh[4], Bo0, aG);  aG = MFMA(whh[5], Bo1, aG);
            aO = MFMA(whh[6], Bo0, aO);  aO = MFMA(whh[7], Bo1, aO);
            if (Lu > 0) {
                aI = MFMA(wih[0], Bi0, aI);  aI = MFMA(wih[1], Bi1, aI);
                aF = MFMA(wih[2], Bi0, aF);  aF = MFMA(wih[3], Bi1, aF);
                aG = MFMA(wih[4], Bi0, aG);  aG = MFMA(wih[5], Bi1, aG);
                aO = MFMA(wih[6], Bi0, aO);  aO = MFMA(wih[7], Bi1, aO);
            }

            // ---- lane-local activations + cell update (4 units r=0..3) ----
            float h0, h1, h2, h3;
            {
                float iv = SIG(aI.x), fv = SIG(aF.x), gv = TH(aG.x), ov = SIG(aO.x);
                c0 = __builtin_fmaf(fv, c0, iv * gv);  h0 = ov * TH(c0);
            }
            {
                float iv = SIG(aI.y), fv = SIG(aF.y), gv = TH(aG.y), ov = SIG(aO.y);
                c1 = __builtin_fmaf(fv, c1, iv * gv);  h1 = ov * TH(c1);
            }
            {
                float iv = SIG(aI.z), fv = SIG(aF.z), gv = TH(aG.z), ov = SIG(aO.z);
                c2 = __builtin_fmaf(fv, c2, iv * gv);  h2 = ov * TH(c2);
            }
            {
                float iv = SIG(aI.w), fv = SIG(aF.w), gv = TH(aG.w), ov = SIG(aO.w);
                c3 = __builtin_fmaf(fv, c3, iv * gv);  h3 = ov * TH(c3);
            }

            // ---- write h (4 consecutive units) as f16, one b64 ----
            v2i hw = { pack2h(h0, h1), pack2h(h2, h3) };
            *(v2i*)&hb[Lu][pcur][lo][16 * wu + hi * 4] = hw;

            if (Lu == 2 && t == NT - 1) {
                float4v ho = {h0, h1, h2, h3};
                *(float4v*)(hl + (size_t)(16 * bg + lo) * 64 + 16 * wu + hi * 4) = ho;
            }
        }
        asm volatile("s_waitcnt lgkmcnt(0)" ::: "memory");
        __builtin_amdgcn_s_barrier();
        __builtin_amdgcn_sched_barrier(0);
    }
#undef MFMA
#undef TH
#undef SIG
}

// ---------------------------------------------------------------------------
// Final linear: out[b][o] = b_out[o] + sum_j h_last[b][j] * W_out[o][j]
// ---------------------------------------------------------------------------
__global__ __launch_bounds__(256) void final_linear(
    const float* __restrict__ hlv, const float* __restrict__ Wout,
    const float* __restrict__ bout, float* __restrict__ out)
{
    __shared__ float w[128];
    int t = threadIdx.x;
    if (t < 128) w[t] = Wout[t];
    __syncthreads();
    const float* h = hlv + (size_t)t * 64;
    float a0 = bout[0], a1 = bout[1];
    #pragma unroll 8
    for (int j = 0; j < 64; ++j) {
        float hv = h[j];
        a0 += hv * w[j];
        a1 += hv * w[64 + j];
    }
    out[t * 2 + 0] = a0;
    out[t * 2 + 1] = a1;
}

// ---------------------------------------------------------------------------
extern "C" void kernel_launch(void* const* d_in, const int* in_sizes, int n_in,
                              void* d_out, int out_size, void* d_ws, size_t ws_size,
                              hipStream_t stream)
{
    const float* x     = (const float*)d_in[0];
    const float* W_ih0 = (const float*)d_in[1];
    const float* W_hh0 = (const float*)d_in[2];
    const float* b_ih0 = (const float*)d_in[3];
    const float* b_hh0 = (const float*)d_in[4];
    const float* W_ih1 = (const float*)d_in[5];
    const float* W_hh1 = (const float*)d_in[6];
    const float* b_ih1 = (const float*)d_in[7];
    const float* b_hh1 = (const float*)d_in[8];
    const float* W_ih2 = (const float*)d_in[9];
    const float* W_hh2 = (const float*)d_in[10];
    const float* b_ih2 = (const float*)d_in[11];
    const float* b_hh2 = (const float*)d_in[12];
    const float* W_out = (const float*)d_in[13];
    const float* b_out = (const float*)d_in[14];
    float* out = (float*)d_out;

    const size_t M = (size_t)NB * NT;                      // 131072
    const size_t XP_BYTES  = M * H4 * sizeof(float);       // 128 MiB
    const size_t WT0_BYTES = 128 * 256 * sizeof(float);
    const size_t WPK_BYTES = 5 * 8192 * sizeof(int);       // 160 KiB
    const size_t HL_BYTES  = NB * 64 * sizeof(float);
    if (ws_size < XP_BYTES + WT0_BYTES + WPK_BYTES + HL_BYTES)
        return;

    char* ws = (char*)d_ws;
    float* XP  = (float*)ws;
    float* WT0 = (float*)(ws + XP_BYTES);
    int*   WPK = (int*)(ws + XP_BYTES + WT0_BYTES);
    float* HL  = (float*)(ws + XP_BYTES + WT0_BYTES + WPK_BYTES);

    // Pre-pack recurrent/input weights into MFMA A-fragment layout.
    pack_wA<<<32, 256, 0, stream>>>(W_hh0, WPK + 0 * 8192);
    pack_wA<<<32, 256, 0, stream>>>(W_hh1, WPK + 1 * 8192);
    pack_wA<<<32, 256, 0, stream>>>(W_ih1, WPK + 2 * 8192);
    pack_wA<<<32, 256, 0, stream>>>(W_hh2, WPK + 3 * 8192);
    pack_wA<<<32, 256, 0, stream>>>(W_ih2, WPK + 4 * 8192);

    // Layer-0 input projection (parallel GEMM, f32 out) — layers 1,2 fused.
    transpose_w<<<128, 256, 0, stream>>>(W_ih0, WT0, 128);
    gemm_xp<128><<<(int)(M / 64), 256, 0, stream>>>(x, WT0, b_ih0, b_hh0, XP);

    // MFMA pipelined 3-layer scan: 16 blocks x 16 batch elements.
    lstm_mfma<<<16, 768, 0, stream>>>(XP, WPK, b_ih1, b_hh1, b_ih2, b_hh2, HL);

    // Final projection.
    final_linear<<<1, 256, 0, stream>>>(HL, W_out, b_out, out);
}

// Round 19
// 741.349 us; speedup vs baseline: 1.0752x; 1.0752x over previous
//
#include <hip/hip_runtime.h>
#include <cstddef>
#include <cstdint>

// Problem constants (from reference): B=256, T=512, I=128, H=64, 4H=256.
#define NB 256
#define NT 512
#define H4 256

typedef _Float16 v2h  __attribute__((ext_vector_type(2)));
typedef _Float16 half8 __attribute__((ext_vector_type(8)));
typedef float float4v __attribute__((ext_vector_type(4)));
typedef int v4i __attribute__((ext_vector_type(4)));
typedef int v2i __attribute__((ext_vector_type(2)));

__device__ __forceinline__ int pack2h(float a, float b) {
    v2h p; p.x = (_Float16)a; p.y = (_Float16)b;
    return __builtin_bit_cast(int, p);
}

// ---------------------------------------------------------------------------
// Pack one weight matrix [256,64] f32 into MFMA A-fragment layout (f16).
// (Identical to round 17 — correctness verified end-to-end.)
// ---------------------------------------------------------------------------
__global__ void pack_wA(const float* __restrict__ W, int* __restrict__ out) {
    int idx = blockIdx.x * 256 + threadIdx.x;   // 0..8191
    int e2 = idx & 3;
    int l  = (idx >> 2) & 63;
    int f  = (idx >> 8) & 7;
    int w  = idx >> 11;
    int g = f >> 1, kt = f & 1;
    int row = 16 * (4 * g + w) + (l & 15);
    int k = 32 * kt + 16 * (e2 >> 1) + ((l >> 4) * 4) + 2 * (e2 & 1);
    out[idx] = pack2h(W[row * 64 + k], W[row * 64 + k + 1]);
}

// ---------------------------------------------------------------------------
// Transpose W [256, K] -> Wt [K, 256] (layer-0 GEMM only)
// ---------------------------------------------------------------------------
__global__ void transpose_w(const float* __restrict__ W, float* __restrict__ Wt, int K) {
    int idx = blockIdx.x * 256 + threadIdx.x;
    if (idx < 256 * K) {
        int n = idx / K, k = idx - n * K;
        Wt[k * 256 + n] = W[idx];
    }
}

// ---------------------------------------------------------------------------
// Input-projection GEMM for layer 0 (K=128), f32 output (round-17 proven).
// ---------------------------------------------------------------------------
template <int K>
__global__ __launch_bounds__(256) void gemm_xp(
    const float* __restrict__ X, const float* __restrict__ Wt,
    const float* __restrict__ b1, const float* __restrict__ b2,
    float* __restrict__ XP)
{
    constexpr int TM = 64;
    constexpr int KC = 16;
    __shared__ __align__(16) float xT[K][TM + 4];
    __shared__ __align__(16) float wc[KC][256];
    const int m0 = blockIdx.x * TM;
    const int t  = threadIdx.x;
    const int cg = (t & 63) * 4;
    const int rg = (t >> 6) * 16;

    for (int idx = t; idx < TM * K; idx += 256) {
        int r = idx / K, k = idx - r * K;
        xT[k][r] = X[(size_t)(m0 + r) * K + k];
    }

    float acc[16][4];
    #pragma unroll
    for (int i = 0; i < 16; ++i)
        #pragma unroll
        for (int j = 0; j < 4; ++j) acc[i][j] = 0.f;

    for (int kc = 0; kc < K; kc += KC) {
        __syncthreads();
        #pragma unroll
        for (int i = 0; i < 4; ++i) {
            int e4 = (t + i * 256) * 4;
            int k = e4 >> 8, n = e4 & 255;
            *(float4*)&wc[k][n] = *(const float4*)&Wt[(size_t)(kc + k) * 256 + n];
        }
        __syncthreads();
        #pragma unroll
        for (int k = 0; k < KC; ++k) {
            float4 w = *(const float4*)&wc[k][cg];
            float xr[16];
            #pragma unroll
            for (int q = 0; q < 4; ++q)
                *(float4*)&xr[q * 4] = *(const float4*)&xT[kc + k][rg + q * 4];
            #pragma unroll
            for (int rr = 0; rr < 16; ++rr) {
                acc[rr][0] += xr[rr] * w.x;
                acc[rr][1] += xr[rr] * w.y;
                acc[rr][2] += xr[rr] * w.z;
                acc[rr][3] += xr[rr] * w.w;
            }
        }
    }

    float bias[4];
    #pragma unroll
    for (int j = 0; j < 4; ++j) bias[j] = b1[cg + j] + b2[cg + j];
    #pragma unroll
    for (int rr = 0; rr < 16; ++rr) {
        float4 o;
        o.x = acc[rr][0] + bias[0];
        o.y = acc[rr][1] + bias[1];
        o.z = acc[rr][2] + bias[2];
        o.w = acc[rr][3] + bias[3];
        *(float4*)&XP[(size_t)(m0 + rg + rr) * 256 + cg] = o;
    }
}

// ---------------------------------------------------------------------------
// MFMA 3-layer wavefront-pipelined LSTM scan, v3.
// Base = round 17 (PASSED, f32 xp). Exactly TWO deltas:
//  1. L0's acc-init xp[t] is depth-2 register-prefetched (f32 float4v slots,
//     consumed 2 steps / 2 barriers later) — round 17 read it from HBM inside
//     the step: ~900-cycle latency serialized behind every block barrier.
//  2. hb rows padded 72 -> 76 f16 (19-word odd stride) to cut the 3M
//     bank-conflict cycles on the b64 h traffic.
// (Round 18's f16-XP path is NOT re-added — it failed correctness.)
// ---------------------------------------------------------------------------
__global__ __launch_bounds__(768) void lstm_mfma(
    const float* __restrict__ xp,     // [B*T, 256] layer-0 xp f32 (incl. biases)
    const int* __restrict__ WPK,      // packed A-frags: 5 matrices x 8192 ints
    const float* __restrict__ bi1, const float* __restrict__ bh1,
    const float* __restrict__ bi2, const float* __restrict__ bh2,
    float* __restrict__ hl)           // [B, 64] layer-2 h at t = NT-1
{
    const int tid = threadIdx.x;
    const int bg = blockIdx.x;           // batches 16bg .. 16bg+15
    const int lane = tid & 63;
    const int lo = lane & 15;            // batch-in-group (MFMA col)
    const int hi = lane >> 4;            // lane group 0..3
    const int w12 = tid >> 6;
    const int Lu = __builtin_amdgcn_readfirstlane(w12 >> 2);   // layer 0..2
    const int wu = __builtin_amdgcn_readfirstlane(w12 & 3);    // unit-tile

    __shared__ __align__(16) _Float16 hb[3][2][16][76];   // 14592 B, odd-word rows
    __shared__ __align__(16) float bias_lds[2][256];      // bi+bh, layers 1,2

    for (int i = tid; i < 3648; i += 768) ((int*)hb)[i] = 0;
    if (tid < 512) {
        int li = tid >> 8, row = tid & 255;
        bias_lds[li][row] = (li ? bi2[row] : bi1[row]) + (li ? bh2[row] : bh1[row]);
    }

    // Whh A-frags -> registers (8 frags x int4; f = gate*2 + ktile)
    half8 whh[8];
    {
        const v4i* wp = (const v4i*)(WPK
            + ((Lu == 0) ? 0 : (Lu == 1) ? 1 : 3) * 8192 + wu * 2048 + lane * 4);
        #pragma unroll
        for (int f = 0; f < 8; ++f) whh[f] = __builtin_bit_cast(half8, wp[f * 64]);
    }
    // Wih A-frags for layers 1,2
    half8 wih[8];
    if (Lu > 0) {
        const v4i* wp = (const v4i*)(WPK
            + ((Lu == 1) ? 2 : 4) * 8192 + wu * 2048 + lane * 4);
        #pragma unroll
        for (int f = 0; f < 8; ++f) wih[f] = __builtin_bit_cast(half8, wp[f * 64]);
    }

    // L0 xp source: rows 64g+16w+hi*4.. of batch 16bg+lo at time t
    const float* xpg = xp + (size_t)(16 * bg + lo) * NT * H4 + 16 * wu + hi * 4;

    // depth-2 prefetch slots (f32): slot0 = even t, slot1 = odd t
    float4v sI0 = {}, sF0 = {}, sG0 = {}, sO0 = {};
    float4v sI1 = {}, sF1 = {}, sG1 = {}, sO1 = {};
    if (Lu == 0) {
        const float* x0 = xpg;            // t = 0
        sI0 = *(const float4v*)(x0);
        sF0 = *(const float4v*)(x0 + 64);
        sG0 = *(const float4v*)(x0 + 128);
        sO0 = *(const float4v*)(x0 + 192);
        const float* x1 = xpg + H4;       // t = 1
        sI1 = *(const float4v*)(x1);
        sF1 = *(const float4v*)(x1 + 64);
        sG1 = *(const float4v*)(x1 + 128);
        sO1 = *(const float4v*)(x1 + 192);
    }

    float c0 = 0.f, c1 = 0.f, c2 = 0.f, c3 = 0.f;   // cell state (4 units/lane)

    asm volatile("s_waitcnt lgkmcnt(0)" ::: "memory");
    __builtin_amdgcn_s_barrier();
    __builtin_amdgcn_sched_barrier(0);

    const float LOG2E = 1.4426950408889634f;
#define SIG(x) __builtin_amdgcn_rcpf(1.f + __builtin_amdgcn_exp2f((x) * -LOG2E))
#define TH(x)  __builtin_fmaf(2.f, __builtin_amdgcn_rcpf(1.f + __builtin_amdgcn_exp2f((x) * (-2.f * LOG2E))), -1.f)
#define MFMA(A, B, C) __builtin_amdgcn_mfma_f32_16x16x32_f16((A), (B), (C), 0, 0, 0)

    for (int s = 0; s < NT + 2; ++s) {
        const int t = s - Lu;                      // wave-uniform
        if ((unsigned)t < NT) {
            const int pprev = (t + 1) & 1, pcur = t & 1;

            // ---- own-h B-fragments (k-tiles 0,1), four b64 reads ----
            const _Float16* hp = &hb[Lu][pprev][lo][hi * 4];
            v2i a0 = *(const v2i*)(hp);
            v2i a1 = *(const v2i*)(hp + 16);
            v2i a2 = *(const v2i*)(hp + 32);
            v2i a3 = *(const v2i*)(hp + 48);
            v4i q0 = {a0.x, a0.y, a1.x, a1.y};
            v4i q1 = {a2.x, a2.y, a3.x, a3.y};
            half8 Bo0 = __builtin_bit_cast(half8, q0);
            half8 Bo1 = __builtin_bit_cast(half8, q1);

            float4v aI, aF, aG, aO;
            half8 Bi0 = {}, Bi1 = {};
            if (Lu == 0) {
                // consume prefetched slot (parity t&1), then refill for t+2
                if (t & 1) { aI = sI1; aF = sF1; aG = sG1; aO = sO1; }
                else       { aI = sI0; aF = sF0; aG = sG0; aO = sO0; }
                int tn = t + 2; if (tn > NT - 1) tn = NT - 1;
                const float* xb = xpg + (size_t)tn * H4;
                float4v lI = *(const float4v*)(xb);
                float4v lF = *(const float4v*)(xb + 64);
                float4v lG = *(const float4v*)(xb + 128);
                float4v lO = *(const float4v*)(xb + 192);
                if (t & 1) { sI1 = lI; sF1 = lF; sG1 = lG; sO1 = lO; }
                else       { sI0 = lI; sF0 = lF; sG0 = lG; sO0 = lO; }
            } else {
                const _Float16* gp = &hb[Lu - 1][pcur][lo][hi * 4];
                v2i b0 = *(const v2i*)(gp);
                v2i b1 = *(const v2i*)(gp + 16);
                v2i b2 = *(const v2i*)(gp + 32);
                v2i b3 = *(const v2i*)(gp + 48);
                v4i u0 = {b0.x, b0.y, b1.x, b1.y};
                v4i u1 = {b2.x, b2.y, b3.x, b3.y};
                Bi0 = __builtin_bit_cast(half8, u0);
                Bi1 = __builtin_bit_cast(half8, u1);
                const float* bp = &bias_lds[Lu - 1][16 * wu + hi * 4];
                aI = *(const float4v*)(bp);
                aF = *(const float4v*)(bp + 64);
                aG = *(const float4v*)(bp + 128);
                aO = *(const float4v*)(bp + 192);
            }

            // ---- MFMA accumulation: gates = Whh.h (+ Wih.g) + init ----
            aI = MFMA(whh[0], Bo0, aI);  aI = MFMA(whh[1], Bo1, aI);
            aF = MFMA(whh[2], Bo0, aF);  aF = MFMA(whh[3], Bo1, aF);
            aG = MFMA(whh[4], Bo0, aG);  aG = MFMA(whh[5], Bo1, aG);
            aO = MFMA(whh[6], Bo0, aO);  aO = MFMA(whh[7], Bo1, aO);
            if (Lu > 0) {
                aI = MFMA(wih[0], Bi0, aI);  aI = MFMA(wih[1], Bi1, aI);
                aF = MFMA(wih[2], Bi0, aF);  aF = MFMA(wih[3], Bi1, aF);
                aG = MFMA(wih[4], Bi0, aG);  aG = MFMA(wih[5], Bi1, aG);
                aO = MFMA(wih[6], Bi0, aO);  aO = MFMA(wih[7], Bi1, aO);
            }

            // ---- lane-local activations + cell update (4 units r=0..3) ----
            float h0, h1, h2, h3;
            {
                float iv = SIG(aI.x), fv = SIG(aF.x), gv = TH(aG.x), ov = SIG(aO.x);
                c0 = __builtin_fmaf(fv, c0, iv * gv);  h0 = ov * TH(c0);
            }
            {
                float iv = SIG(aI.y), fv = SIG(aF.y), gv = TH(aG.y), ov = SIG(aO.y);
                c1 = __builtin_fmaf(fv, c1, iv * gv);  h1 = ov * TH(c1);
            }
            {
                float iv = SIG(aI.z), fv = SIG(aF.z), gv = TH(aG.z), ov = SIG(aO.z);
                c2 = __builtin_fmaf(fv, c2, iv * gv);  h2 = ov * TH(c2);
            }
            {
                float iv = SIG(aI.w), fv = SIG(aF.w), gv = TH(aG.w), ov = SIG(aO.w);
                c3 = __builtin_fmaf(fv, c3, iv * gv);  h3 = ov * TH(c3);
            }

            // ---- write h (4 consecutive units) as f16, one b64 ----
            v2i hw = { pack2h(h0, h1), pack2h(h2, h3) };
            *(v2i*)&hb[Lu][pcur][lo][16 * wu + hi * 4] = hw;

            if (Lu == 2 && t == NT - 1) {
                float4v ho = {h0, h1, h2, h3};
                *(float4v*)(hl + (size_t)(16 * bg + lo) * 64 + 16 * wu + hi * 4) = ho;
            }
        }
        asm volatile("s_waitcnt lgkmcnt(0)" ::: "memory");
        __builtin_amdgcn_s_barrier();
        __builtin_amdgcn_sched_barrier(0);
    }
#undef MFMA
#undef TH
#undef SIG
}

// ---------------------------------------------------------------------------
// Final linear: out[b][o] = b_out[o] + sum_j h_last[b][j] * W_out[o][j]
// ---------------------------------------------------------------------------
__global__ __launch_bounds__(256) void final_linear(
    const float* __restrict__ hlv, const float* __restrict__ Wout,
    const float* __restrict__ bout, float* __restrict__ out)
{
    __shared__ float w[128];
    int t = threadIdx.x;
    if (t < 128) w[t] = Wout[t];
    __syncthreads();
    const float* h = hlv + (size_t)t * 64;
    float a0 = bout[0], a1 = bout[1];
    #pragma unroll 8
    for (int j = 0; j < 64; ++j) {
        float hv = h[j];
        a0 += hv * w[j];
        a1 += hv * w[64 + j];
    }
    out[t * 2 + 0] = a0;
    out[t * 2 + 1] = a1;
}

// ---------------------------------------------------------------------------
extern "C" void kernel_launch(void* const* d_in, const int* in_sizes, int n_in,
                              void* d_out, int out_size, void* d_ws, size_t ws_size,
                              hipStream_t stream)
{
    const float* x     = (const float*)d_in[0];
    const float* W_ih0 = (const float*)d_in[1];
    const float* W_hh0 = (const float*)d_in[2];
    const float* b_ih0 = (const float*)d_in[3];
    const float* b_hh0 = (const float*)d_in[4];
    const float* W_ih1 = (const float*)d_in[5];
    const float* W_hh1 = (const float*)d_in[6];
    const float* b_ih1 = (const float*)d_in[7];
    const float* b_hh1 = (const float*)d_in[8];
    const float* W_ih2 = (const float*)d_in[9];
    const float* W_hh2 = (const float*)d_in[10];
    const float* b_ih2 = (const float*)d_in[11];
    const float* b_hh2 = (const float*)d_in[12];
    const float* W_out = (const float*)d_in[13];
    const float* b_out = (const float*)d_in[14];
    float* out = (float*)d_out;

    const size_t M = (size_t)NB * NT;                      // 131072
    const size_t XP_BYTES  = M * H4 * sizeof(float);       // 128 MiB
    const size_t WT0_BYTES = 128 * 256 * sizeof(float);
    const size_t WPK_BYTES = 5 * 8192 * sizeof(int);       // 160 KiB
    const size_t HL_BYTES  = NB * 64 * sizeof(float);
    if (ws_size < XP_BYTES + WT0_BYTES + WPK_BYTES + HL_BYTES)
        return;

    char* ws = (char*)d_ws;
    float* XP  = (float*)ws;
    float* WT0 = (float*)(ws + XP_BYTES);
    int*   WPK = (int*)(ws + XP_BYTES + WT0_BYTES);
    float* HL  = (float*)(ws + XP_BYTES + WT0_BYTES + WPK_BYTES);

    // Pre-pack recurrent/input weights into MFMA A-fragment layout.
    pack_wA<<<32, 256, 0, stream>>>(W_hh0, WPK + 0 * 8192);
    pack_wA<<<32, 256, 0, stream>>>(W_hh1, WPK + 1 * 8192);
    pack_wA<<<32, 256, 0, stream>>>(W_ih1, WPK + 2 * 8192);
    pack_wA<<<32, 256, 0, stream>>>(W_hh2, WPK + 3 * 8192);
    pack_wA<<<32, 256, 0, stream>>>(W_ih2, WPK + 4 * 8192);

    // Layer-0 input projection (parallel GEMM, f32 out) — layers 1,2 fused.
    transpose_w<<<128, 256, 0, stream>>>(W_ih0, WT0, 128);
    gemm_xp<128><<<(int)(M / 64), 256, 0, stream>>>(x, WT0, b_ih0, b_hh0, XP);

    // MFMA pipelined 3-layer scan: 16 blocks x 16 batch elements.
    lstm_mfma<<<16, 768, 0, stream>>>(XP, WPK, b_ih1, b_hh1, b_ih2, b_hh2, HL);

    // Final projection.
    final_linear<<<1, 256, 0, stream>>>(HL, W_out, b_out, out);
}